// Round 8
// baseline (282.891 us; speedup 1.0000x reference)
//
#include <hip/hip_runtime.h>
#include <math.h>

#define N_NODES 50000
#define EDGES   800000
#define ETOT    (EDGES + N_NODES)
#define HID     128
#define NH      4

typedef __attribute__((ext_vector_type(8))) short short8;
typedef __attribute__((ext_vector_type(4))) float floatx4;

__device__ inline unsigned short f2bf(float f) {
    unsigned int u = __float_as_uint(f);
    u = u + 0x7FFFu + ((u >> 16) & 1u);   // RNE
    return (unsigned short)(u >> 16);
}

// ---------------------------------------------------------------------------
// CSR build via radix binning by dst (line-dense writes)
// ---------------------------------------------------------------------------
#define NB 391
#define CHUNK 4096
#define BIN_BLOCKS ((ETOT + CHUNK - 1) / CHUNK)   // 208

__global__ __launch_bounds__(256) void bin_count_kernel(const int* __restrict__ ei,
                                                        int* __restrict__ histG) {
    __shared__ int histL[NB];
    int t = threadIdx.x;
    for (int b = t; b < NB; b += 256) histL[b] = 0;
    __syncthreads();
    int base = blockIdx.x * CHUNK;
#pragma unroll
    for (int j = 0; j < 16; j++) {
        int e = base + j * 256 + t;
        if (e < ETOT) {
            int d = (e < EDGES) ? ei[EDGES + e] : (e - EDGES);
            atomicAdd(&histL[d >> 7], 1);
        }
    }
    __syncthreads();
    for (int b = t; b < NB; b += 256) {
        int c = histL[b];
        if (c) atomicAdd(&histG[b], c);
    }
}

__global__ __launch_bounds__(512) void bucket_scan_kernel(const int* __restrict__ histG,
                                                          int* __restrict__ bucket_base,
                                                          int* __restrict__ bucket_cursor) {
    __shared__ int sh[512];
    int t = threadIdx.x;
    int v = (t < NB) ? histG[t] : 0;
    sh[t] = v;
    __syncthreads();
    for (int off = 1; off < 512; off <<= 1) {
        int x = sh[t];
        int add = (t >= off) ? sh[t - off] : 0;
        __syncthreads();
        sh[t] = x + add;
        __syncthreads();
    }
    if (t < NB) { int ex = sh[t] - v; bucket_base[t] = ex; bucket_cursor[t] = ex; }
    if (t == 511) bucket_base[NB] = sh[511];
}

__global__ __launch_bounds__(256) void bin_scatter_kernel(const int* __restrict__ ei,
                                                          int* __restrict__ bucket_cursor,
                                                          int2* __restrict__ binned) {
    __shared__ int histL[NB];
    int t = threadIdx.x;
    for (int b = t; b < NB; b += 256) histL[b] = 0;
    __syncthreads();
    int base = blockIdx.x * CHUNK;
#pragma unroll
    for (int j = 0; j < 16; j++) {
        int e = base + j * 256 + t;
        if (e < ETOT) {
            int d = (e < EDGES) ? ei[EDGES + e] : (e - EDGES);
            atomicAdd(&histL[d >> 7], 1);
        }
    }
    __syncthreads();
    for (int b = t; b < NB; b += 256) {
        int c = histL[b];
        histL[b] = c ? atomicAdd(&bucket_cursor[b], c) : 0;
    }
    __syncthreads();
#pragma unroll
    for (int j = 0; j < 16; j++) {
        int e = base + j * 256 + t;
        if (e < ETOT) {
            int s, d;
            if (e < EDGES) { s = ei[e]; d = ei[EDGES + e]; }
            else           { s = d = e - EDGES; }
            int pos = atomicAdd(&histL[d >> 7], 1);
            binned[pos] = make_int2(s, d);
        }
    }
}

__global__ __launch_bounds__(256) void bin_finalize_kernel(const int2* __restrict__ binned,
                                                           const int* __restrict__ bucket_base,
                                                           int* __restrict__ offsets,
                                                           int* __restrict__ csr) {
    __shared__ int histN[128];
    __shared__ int excl[128];
    int b = blockIdx.x, t = threadIdx.x;
    int n0 = b << 7;
    int ebase = bucket_base[b];
    int ecnt  = bucket_base[b + 1] - ebase;
    if (t < 128) histN[t] = 0;
    __syncthreads();
    for (int j = t; j < ecnt; j += 256)
        atomicAdd(&histN[binned[ebase + j].y - n0], 1);
    __syncthreads();
    int v = (t < 128) ? histN[t] : 0;
    if (t < 128) excl[t] = v;
    __syncthreads();
    for (int off = 1; off < 128; off <<= 1) {
        int x = 0, add = 0;
        if (t < 128) { x = excl[t]; if (t >= off) add = excl[t - off]; }
        __syncthreads();
        if (t < 128) excl[t] = x + add;
        __syncthreads();
    }
    if (t < 128) {
        int ex = excl[t] - v;
        int n = n0 + t;
        if (n < N_NODES) offsets[n] = ebase + ex;
        histN[t] = ex;
    }
    if (b == NB - 1 && t == 0) offsets[N_NODES] = ETOT;
    __syncthreads();
    for (int j = t; j < ecnt; j += 256) {
        int2 e = binned[ebase + j];
        int pos = atomicAdd(&histN[e.y - n0], 1);
        csr[ebase + pos] = e.x;
    }
}

// ---------------------------------------------------------------------------
// coef: fold bias+BN into per-channel affine. [A1|B1|A2|B2] (128 each)
// ---------------------------------------------------------------------------
__global__ void coef_kernel(const float* __restrict__ b1, const float* __restrict__ g1,
                            const float* __restrict__ be1, const float* __restrict__ mn1,
                            const float* __restrict__ vr1,
                            const float* __restrict__ b2, const float* __restrict__ g2,
                            const float* __restrict__ be2, const float* __restrict__ mn2,
                            const float* __restrict__ vr2, float* __restrict__ coef) {
    int t = threadIdx.x;
    if (t < 128) {
        float sc = g1[t] * rsqrtf(vr1[t] + 1e-5f);
        coef[t]       = sc;
        coef[128 + t] = be1[t] + (b1[t] - mn1[t]) * sc;
    } else {
        int c = t - 128;
        float sc = g2[c] * rsqrtf(vr2[c] + 1e-5f);
        coef[256 + c] = sc;
        coef[384 + c] = be2[c] + (b2[c] - mn2[c]) * sc;
    }
}

// ---------------------------------------------------------------------------
// W transpose + bf16 convert: Wt[n][k] = bf16(W[k][n])
// ---------------------------------------------------------------------------
__global__ void wtrans_kernel(const float* __restrict__ W1, const float* __restrict__ W2,
                              unsigned short* __restrict__ Wt1, unsigned short* __restrict__ Wt2) {
    int i = blockIdx.x * 256 + threadIdx.x;
    if (i < 256 * 128) { int k = i >> 7, n = i & 127; Wt1[n * 256 + k] = f2bf(W1[i]); }
    if (i < 128 * 128) { int k = i >> 7, n = i & 127; Wt2[n * 128 + k] = f2bf(W2[i]); }
}

// ---------------------------------------------------------------------------
// MFMA GEMM (bf16 in, fp32 acc) + fused attention dots + bf16 H output.
// ---------------------------------------------------------------------------
#define GR   128
#define KC   64
#define PADK 88
#define PADH 136

union Smem {
    struct { unsigned short Xs[GR][PADK]; unsigned short Ws[HID][PADK]; } s;
    unsigned short Hs[GR][PADH];
};

template<bool XBF16>
__global__ __launch_bounds__(256) void gemm_att_kernel(const void* __restrict__ Xv,
                                                       const unsigned short* __restrict__ Wt,
                                                       const float* __restrict__ att_src,
                                                       const float* __restrict__ att_dst,
                                                       unsigned short* __restrict__ Hout,
                                                       float* __restrict__ aS,
                                                       float* __restrict__ aD, int K) {
    __shared__ Smem sm;
    int t = threadIdx.x, lane = t & 63, w = t >> 6;
    int quad = lane >> 4, nl = lane & 15;
    int rowBase = blockIdx.x * GR;

    floatx4 acc[2][8];
    floatx4 zero = {0.f, 0.f, 0.f, 0.f};
#pragma unroll
    for (int a = 0; a < 2; a++)
#pragma unroll
        for (int b = 0; b < 8; b++) acc[a][b] = zero;

    const float*          Xf = (const float*)Xv;
    const unsigned short* Xb = (const unsigned short*)Xv;

    for (int k0 = 0; k0 < K; k0 += KC) {
#pragma unroll
        for (int it = 0; it < 4; it++) {
            int s5 = t + it * 256;
            int row = s5 >> 3, kg = s5 & 7;
            int gr = rowBase + row;
            unsigned short tmp[8];
            if (XBF16) {
                uint4 v = make_uint4(0, 0, 0, 0);
                if (gr < N_NODES) v = *(const uint4*)&Xb[(unsigned)(gr * K + k0 + kg * 8)];
                *(uint4*)tmp = v;
            } else {
                float4 v0 = make_float4(0, 0, 0, 0), v1 = v0;
                if (gr < N_NODES) {
                    const float* p = &Xf[(unsigned)(gr * K + k0 + kg * 8)];
                    v0 = *(const float4*)p;
                    v1 = *(const float4*)(p + 4);
                }
                tmp[0] = f2bf(v0.x); tmp[1] = f2bf(v0.y); tmp[2] = f2bf(v0.z); tmp[3] = f2bf(v0.w);
                tmp[4] = f2bf(v1.x); tmp[5] = f2bf(v1.y); tmp[6] = f2bf(v1.z); tmp[7] = f2bf(v1.w);
            }
            *(uint4*)&sm.s.Xs[row][kg * 8] = *(uint4*)tmp;
        }
#pragma unroll
        for (int it = 0; it < 4; it++) {
            int s5 = t + it * 256;
            int n = s5 >> 3, kg = s5 & 7;
            *(uint4*)&sm.s.Ws[n][kg * 8] = *(const uint4*)&Wt[(unsigned)(n * K + k0 + kg * 8)];
        }
        __syncthreads();
#pragma unroll
        for (int ks = 0; ks < 2; ks++) {
            int kb = ks * 32 + quad * 8;
            short8 a0 = *(const short8*)&sm.s.Xs[w * 32 + nl][kb];
            short8 a1 = *(const short8*)&sm.s.Xs[w * 32 + 16 + nl][kb];
#pragma unroll
            for (int ct = 0; ct < 8; ct++) {
                short8 b = *(const short8*)&sm.s.Ws[ct * 16 + nl][kb];
                acc[0][ct] = __builtin_amdgcn_mfma_f32_16x16x32_bf16(a0, b, acc[0][ct], 0, 0, 0);
                acc[1][ct] = __builtin_amdgcn_mfma_f32_16x16x32_bf16(a1, b, acc[1][ct], 0, 0, 0);
            }
        }
        __syncthreads();
    }

#pragma unroll
    for (int rt = 0; rt < 2; rt++)
#pragma unroll
        for (int ct = 0; ct < 8; ct++)
#pragma unroll
            for (int r = 0; r < 4; r++)
                sm.Hs[w * 32 + rt * 16 + quad * 4 + r][ct * 16 + nl] = f2bf(acc[rt][ct][r]);

    float asv[8], adv[8];
    {
        const float* ap = &att_src[nl * 8];
        const float* dp = &att_dst[nl * 8];
        *(float4*)&asv[0] = *(const float4*)ap;  *(float4*)&asv[4] = *(const float4*)(ap + 4);
        *(float4*)&adv[0] = *(const float4*)dp;  *(float4*)&adv[4] = *(const float4*)(dp + 4);
    }
    int hd = nl >> 2;
#pragma unroll
    for (int it = 0; it < 8; it++) {
        int rl = w * 32 + it * 4 + quad;
        int grow = rowBase + rl;
        uint4 v = *(const uint4*)&sm.Hs[rl][nl * 8];
        float f[8];
        f[0] = __uint_as_float(v.x << 16); f[1] = __uint_as_float(v.x & 0xffff0000u);
        f[2] = __uint_as_float(v.y << 16); f[3] = __uint_as_float(v.y & 0xffff0000u);
        f[4] = __uint_as_float(v.z << 16); f[5] = __uint_as_float(v.z & 0xffff0000u);
        f[6] = __uint_as_float(v.w << 16); f[7] = __uint_as_float(v.w & 0xffff0000u);
        float ds = 0.f, dd = 0.f;
#pragma unroll
        for (int j = 0; j < 8; j++) {
            ds = fmaf(f[j], asv[j], ds);
            dd = fmaf(f[j], adv[j], dd);
        }
        ds += __shfl_xor(ds, 1); ds += __shfl_xor(ds, 2);
        dd += __shfl_xor(dd, 1); dd += __shfl_xor(dd, 2);
        if (grow < N_NODES) {
            *(uint4*)&Hout[(unsigned)(grow * HID + nl * 8)] = v;
            if ((nl & 3) == 0) { aS[grow * 4 + hd] = ds; aD[grow * 4 + hd] = dd; }
        }
    }
}

// ---------------------------------------------------------------------------
// Fused softmax + aggregate, one wave per node.
// Phase A (head-parallel): 16 lanes per head; lane handles its head over edges
// strided by 16 (4 cached regs -> deg<=64; generic fallback beyond). Reductions
// are 4-round 16-lane shuffles. m/rd/adh end up in the right lane for phase B.
// Phase B: lane covers channel pair c={2*lane,2*lane+1}; unroll 8 -> 8 random
// h-loads in flight. Byte-offset LDS table, 32-bit addressing throughout.
// ---------------------------------------------------------------------------
#define ECAP 64
#define ASTRIDE 68

template<bool OUTBF16>
__global__ __launch_bounds__(256) void gather_kernel(const unsigned short* __restrict__ hfeat,
                                                     const float* __restrict__ a_s,
                                                     const float* __restrict__ a_d,
                                                     const int* __restrict__ offsets,
                                                     const int* __restrict__ csr,
                                                     const float* __restrict__ coefA,
                                                     const float* __restrict__ coefB,
                                                     void* __restrict__ outv) {
    __shared__ float alphaT[4][4][ASTRIDE];   // 4352 B
    __shared__ int   offS[4][ECAP];           // 1024 B
    int t = threadIdx.x, lane = t & 63, ws = t >> 6;
    int h = lane >> 4, l16 = lane & 15;
    int n = blockIdx.x * 4 + ws;
    int start = offsets[n], end = offsets[n + 1];
    int deg = end - start;
    float adh = a_d[(unsigned)(n * 4 + h)];

    // ---- Phase A ----
    float e[4];
    int   sreg[4];
#pragma unroll
    for (int it = 0; it < 4; it++) {
        int j = l16 + it * 16;
        e[it] = -1e30f;
        if (j < deg) {
            int s = csr[start + j];
            sreg[it] = s;
            float as = a_s[(unsigned)(s * 4 + h)];
            float v = as + adh;
            e[it] = v > 0.f ? v : 0.2f * v;
        }
    }
    float m = fmaxf(fmaxf(e[0], e[1]), fmaxf(e[2], e[3]));
    for (int j = ECAP + l16; j < deg; j += 16) {   // rare fallback
        int s = csr[start + j];
        float as = a_s[(unsigned)(s * 4 + h)];
        float v = as + adh; v = v > 0.f ? v : 0.2f * v;
        m = fmaxf(m, v);
    }
#pragma unroll
    for (int off = 1; off < 16; off <<= 1) m = fmaxf(m, __shfl_xor(m, off));

    float x[4];
    float d = 0.f;
#pragma unroll
    for (int it = 0; it < 4; it++) { x[it] = __expf(e[it] - m); d += x[it]; }
    for (int j = ECAP + l16; j < deg; j += 16) {   // rare fallback
        int s = csr[start + j];
        float as = a_s[(unsigned)(s * 4 + h)];
        float v = as + adh; v = v > 0.f ? v : 0.2f * v;
        d += __expf(v - m);
    }
#pragma unroll
    for (int off = 1; off < 16; off <<= 1) d += __shfl_xor(d, off);
    float rd = 1.0f / (d + 1e-16f);

#pragma unroll
    for (int it = 0; it < 4; it++) {
        int j = l16 + it * 16;
        if (j < deg) {
            alphaT[ws][h][j] = x[it] * rd;
            if (h == 0) offS[ws][j] = sreg[it] << 8;   // byte offset of h row
        }
    }
    __syncthreads();

    // ---- Phase B ----
    int c = lane * 2;
    int lane4 = lane * 4;
    const char* hbase = (const char*)hfeat;

    float acc0 = 0.f, acc1 = 0.f;
    int cap = deg < ECAP ? deg : ECAP;
    int j = 0;
    for (; j + 7 < cap; j += 8) {
        unsigned o[8]; float a[8]; unsigned v[8];
#pragma unroll
        for (int u = 0; u < 8; u++) o[u] = (unsigned)(offS[ws][j + u] + lane4);
#pragma unroll
        for (int u = 0; u < 8; u++) a[u] = alphaT[ws][h][j + u];
#pragma unroll
        for (int u = 0; u < 8; u++) v[u] = *(const unsigned int*)(hbase + o[u]);
#pragma unroll
        for (int u = 0; u < 8; u++) {
            acc0 = fmaf(__uint_as_float(v[u] << 16),         a[u], acc0);
            acc1 = fmaf(__uint_as_float(v[u] & 0xffff0000u), a[u], acc1);
        }
    }
    for (; j < cap; j++) {
        unsigned o = (unsigned)(offS[ws][j] + lane4);
        float al = alphaT[ws][h][j];
        unsigned int v = *(const unsigned int*)(hbase + o);
        acc0 = fmaf(__uint_as_float(v << 16),         al, acc0);
        acc1 = fmaf(__uint_as_float(v & 0xffff0000u), al, acc1);
    }
    for (; j < deg; j++) {   // rare fallback: recompute alpha (right head already)
        int s = csr[start + j];
        float as = a_s[(unsigned)(s * 4 + h)];
        float v2 = as + adh; v2 = v2 > 0.f ? v2 : 0.2f * v2;
        float al = __expf(v2 - m) * rd;
        unsigned int v = *(const unsigned int*)(hbase + (unsigned)((s << 8) + lane4));
        acc0 = fmaf(__uint_as_float(v << 16),         al, acc0);
        acc1 = fmaf(__uint_as_float(v & 0xffff0000u), al, acc1);
    }
    float2 cA = *(const float2*)&coefA[c];
    float2 cB = *(const float2*)&coefB[c];
    float o0 = fmaxf(fmaf(acc0, cA.x, cB.x), 0.f);
    float o1 = fmaxf(fmaf(acc1, cA.y, cB.y), 0.f);
    if (OUTBF16) {
        unsigned int pk = (unsigned int)f2bf(o0) | ((unsigned int)f2bf(o1) << 16);
        ((unsigned int*)outv)[(unsigned)(n * 64 + lane)] = pk;
    } else {
        ((float2*)outv)[(unsigned)(n * 64 + lane)] = make_float2(o0, o1);
    }
}

// ---------------------------------------------------------------------------
extern "C" void kernel_launch(void* const* d_in, const int* in_sizes, int n_in,
                              void* d_out, int out_size, void* d_ws, size_t ws_size,
                              hipStream_t stream) {
    const float* x    = (const float*)d_in[0];
    const int*   ei   = (const int*)d_in[1];
    const float* W1   = (const float*)d_in[2];
    const float* as1  = (const float*)d_in[3];
    const float* ad1  = (const float*)d_in[4];
    const float* b1   = (const float*)d_in[5];
    const float* g1   = (const float*)d_in[6];
    const float* be1  = (const float*)d_in[7];
    const float* mn1  = (const float*)d_in[8];
    const float* vr1  = (const float*)d_in[9];
    const float* W2   = (const float*)d_in[10];
    const float* as2  = (const float*)d_in[11];
    const float* ad2  = (const float*)d_in[12];
    const float* b2   = (const float*)d_in[13];
    const float* g2   = (const float*)d_in[14];
    const float* be2  = (const float*)d_in[15];
    const float* mn2  = (const float*)d_in[16];
    const float* vr2  = (const float*)d_in[17];
    float* out = (float*)d_out;

    unsigned short* hb  = (unsigned short*)d_ws;                  // N*128 bf16
    unsigned short* x2b = hb + (size_t)N_NODES * HID;             // N*128 bf16
    unsigned short* Wt1 = x2b + (size_t)N_NODES * HID;            // 128*256
    unsigned short* Wt2 = Wt1 + 128 * 256;                        // 128*128
    float* aS    = (float*)(Wt2 + 128 * 128);                     // N*4
    float* aD    = aS + N_NODES * NH;                             // N*4
    float* coef  = aD + N_NODES * NH;                             // 512
    int* histG         = (int*)(coef + 512);                      // NB
    int* bucket_base   = histG + NB;                              // NB+1
    int* bucket_cursor = bucket_base + NB + 1;                    // NB
    int* offsets       = bucket_cursor + NB;                      // N+1
    int2* binned       = (int2*)(offsets + N_NODES + 1);          // ETOT int2
    int* csr           = (int*)(binned + ETOT);                   // ETOT

    hipMemsetAsync(histG, 0, NB * sizeof(int), stream);
    bin_count_kernel<<<BIN_BLOCKS, 256, 0, stream>>>(ei, histG);
    bucket_scan_kernel<<<1, 512, 0, stream>>>(histG, bucket_base, bucket_cursor);
    bin_scatter_kernel<<<BIN_BLOCKS, 256, 0, stream>>>(ei, bucket_cursor, binned);
    bin_finalize_kernel<<<NB, 256, 0, stream>>>(binned, bucket_base, offsets, csr);
    coef_kernel<<<1, 256, 0, stream>>>(b1, g1, be1, mn1, vr1, b2, g2, be2, mn2, vr2, coef);
    wtrans_kernel<<<128, 256, 0, stream>>>(W1, W2, Wt1, Wt2);

    int gemmGrid = (N_NODES + GR - 1) / GR;   // 391
    int nodeGrid = N_NODES / 4;               // 12500, exact (4 waves/block)

    // Layer 1
    gemm_att_kernel<false><<<gemmGrid, 256, 0, stream>>>(x, Wt1, as1, ad1, hb, aS, aD, 256);
    gather_kernel<true><<<nodeGrid, 256, 0, stream>>>(hb, aS, aD, offsets, csr,
                                                      coef, coef + 128, (void*)x2b);
    // Layer 2
    gemm_att_kernel<true><<<gemmGrid, 256, 0, stream>>>(x2b, Wt2, as2, ad2, hb, aS, aD, 128);
    gather_kernel<false><<<nodeGrid, 256, 0, stream>>>(hb, aS, aD, offsets, csr,
                                                       coef + 256, coef + 384, (void*)out);
}

// Round 9
// 264.733 us; speedup vs baseline: 1.0686x; 1.0686x over previous
//
#include <hip/hip_runtime.h>
#include <math.h>

#define N_NODES 50000
#define EDGES   800000
#define ETOT    (EDGES + N_NODES)
#define HID     128
#define NH      4

typedef __attribute__((ext_vector_type(8))) short short8;
typedef __attribute__((ext_vector_type(4))) float floatx4;

__device__ inline unsigned short f2bf(float f) {
    unsigned int u = __float_as_uint(f);
    u = u + 0x7FFFu + ((u >> 16) & 1u);   // RNE
    return (unsigned short)(u >> 16);
}

// ---------------------------------------------------------------------------
// CSR build, 2 kernels: direct bucketed scatter (fixed-capacity buckets,
// packed (s<<7)|(d&127) ints), then per-bucket finalize into gapped csr.
// Bucket = 128 nodes. Edges/bucket ~ Poisson(2176), sigma 47; BCAP = 2688.
// ---------------------------------------------------------------------------
#define NB 391
#define BCAP 2688
#define CHUNK 4096
#define BIN_BLOCKS ((ETOT + CHUNK - 1) / CHUNK)   // 208

__global__ __launch_bounds__(256) void init_cursor_kernel(int* __restrict__ cursor) {
    int t = blockIdx.x * 256 + threadIdx.x;
    if (t < NB) cursor[t] = t * BCAP;
}

__global__ __launch_bounds__(256) void bin_scatter_kernel(const int* __restrict__ ei,
                                                          int* __restrict__ cursor,
                                                          int* __restrict__ binned) {
    __shared__ int histL[NB];
    int t = threadIdx.x;
    for (int b = t; b < NB; b += 256) histL[b] = 0;
    __syncthreads();
    int base = blockIdx.x * CHUNK;
#pragma unroll
    for (int j = 0; j < 16; j++) {
        int e = base + j * 256 + t;
        if (e < ETOT) {
            int d = (e < EDGES) ? ei[EDGES + e] : (e - EDGES);
            atomicAdd(&histL[d >> 7], 1);
        }
    }
    __syncthreads();
    for (int b = t; b < NB; b += 256) {
        int c = histL[b];
        histL[b] = c ? atomicAdd(&cursor[b], c) : 0;   // global reservation
    }
    __syncthreads();
#pragma unroll
    for (int j = 0; j < 16; j++) {
        int e = base + j * 256 + t;
        if (e < ETOT) {
            int s, d;
            if (e < EDGES) { s = ei[e]; d = ei[EDGES + e]; }
            else           { s = d = e - EDGES; }
            int bb = d >> 7;
            int pos = atomicAdd(&histL[bb], 1);
            if (pos < (bb + 1) * BCAP)                 // safety clamp
                binned[pos] = (s << 7) | (d & 127);
        }
    }
}

__global__ __launch_bounds__(256) void bin_finalize_kernel(const int* __restrict__ binned,
                                                           const int* __restrict__ cursor,
                                                           int* __restrict__ starts,
                                                           int* __restrict__ degs,
                                                           int* __restrict__ csr) {
    __shared__ int histN[128];
    __shared__ int excl[128];
    int b = blockIdx.x, t = threadIdx.x;
    int n0 = b << 7;
    int S = b * BCAP;
    int cnt = cursor[b] - S;
    if (cnt > BCAP) cnt = BCAP;
    if (t < 128) histN[t] = 0;
    __syncthreads();
    for (int j = t; j < cnt; j += 256)
        atomicAdd(&histN[binned[S + j] & 127], 1);
    __syncthreads();
    int v = (t < 128) ? histN[t] : 0;
    if (t < 128) excl[t] = v;
    __syncthreads();
    for (int off = 1; off < 128; off <<= 1) {
        int x = 0, add = 0;
        if (t < 128) { x = excl[t]; if (t >= off) add = excl[t - off]; }
        __syncthreads();
        if (t < 128) excl[t] = x + add;
        __syncthreads();
    }
    if (t < 128) {
        int ex = excl[t] - v;
        int n = n0 + t;
        if (n < N_NODES) { starts[n] = S + ex; degs[n] = v; }
        histN[t] = ex;                 // reuse as within-bucket cursor
    }
    __syncthreads();
    for (int j = t; j < cnt; j += 256) {
        int e = binned[S + j];
        int pos = atomicAdd(&histN[e & 127], 1);
        csr[S + pos] = e >> 7;
    }
}

// ---------------------------------------------------------------------------
// W transpose + bf16 convert; block 0 also folds bias+BN into coef.
// ---------------------------------------------------------------------------
__global__ void wtrans_coef_kernel(const float* __restrict__ W1, const float* __restrict__ W2,
                                   unsigned short* __restrict__ Wt1, unsigned short* __restrict__ Wt2,
                                   const float* __restrict__ b1, const float* __restrict__ g1,
                                   const float* __restrict__ be1, const float* __restrict__ mn1,
                                   const float* __restrict__ vr1,
                                   const float* __restrict__ b2, const float* __restrict__ g2,
                                   const float* __restrict__ be2, const float* __restrict__ mn2,
                                   const float* __restrict__ vr2, float* __restrict__ coef) {
    int i = blockIdx.x * 256 + threadIdx.x;
    if (i < 256 * 128) { int k = i >> 7, n = i & 127; Wt1[n * 256 + k] = f2bf(W1[i]); }
    if (i < 128 * 128) { int k = i >> 7, n = i & 127; Wt2[n * 128 + k] = f2bf(W2[i]); }
    if (blockIdx.x == 0) {
        int t = threadIdx.x;
        if (t < 128) {
            float sc = g1[t] * rsqrtf(vr1[t] + 1e-5f);
            coef[t]       = sc;
            coef[128 + t] = be1[t] + (b1[t] - mn1[t]) * sc;
        } else {
            int c = t - 128;
            float sc = g2[c] * rsqrtf(vr2[c] + 1e-5f);
            coef[256 + c] = sc;
            coef[384 + c] = be2[c] + (b2[c] - mn2[c]) * sc;
        }
    }
}

// ---------------------------------------------------------------------------
// MFMA GEMM (bf16, fp32 acc) + fused att dots + bf16 H out.
// 64-row x 128-col block tile (782 blocks -> ~3 blocks/CU in flight),
// 4 waves x (1 row-tile x 8 col-tiles), KC=64. LDS 33.8KB -> 4 blocks/CU cap.
// ---------------------------------------------------------------------------
#define GR   64
#define KC   64
#define PADK 88
#define PADH 136

union Smem {
    struct { unsigned short Xs[GR][PADK]; unsigned short Ws[HID][PADK]; } s;
    unsigned short Hs[GR][PADH];
};

template<bool XBF16>
__global__ __launch_bounds__(256) void gemm_att_kernel(const void* __restrict__ Xv,
                                                       const unsigned short* __restrict__ Wt,
                                                       const float* __restrict__ att_src,
                                                       const float* __restrict__ att_dst,
                                                       unsigned short* __restrict__ Hout,
                                                       float* __restrict__ aS,
                                                       float* __restrict__ aD, int K) {
    __shared__ Smem sm;
    int t = threadIdx.x, lane = t & 63, w = t >> 6;
    int quad = lane >> 4, nl = lane & 15;
    int rowBase = blockIdx.x * GR;

    floatx4 acc[8];
    floatx4 zero = {0.f, 0.f, 0.f, 0.f};
#pragma unroll
    for (int b = 0; b < 8; b++) acc[b] = zero;

    const float*          Xf = (const float*)Xv;
    const unsigned short* Xb = (const unsigned short*)Xv;

    for (int k0 = 0; k0 < K; k0 += KC) {
        // stage X tile (64 rows x 64 k) as bf16: 512 uint4 slots, 2 iters
#pragma unroll
        for (int it = 0; it < 2; it++) {
            int s5 = t + it * 256;
            int row = s5 >> 3, kg = s5 & 7;
            int gr = rowBase + row;
            unsigned short tmp[8];
            if (XBF16) {
                uint4 v = make_uint4(0, 0, 0, 0);
                if (gr < N_NODES) v = *(const uint4*)&Xb[(unsigned)(gr * K + k0 + kg * 8)];
                *(uint4*)tmp = v;
            } else {
                float4 v0 = make_float4(0, 0, 0, 0), v1 = v0;
                if (gr < N_NODES) {
                    const float* p = &Xf[(unsigned)(gr * K + k0 + kg * 8)];
                    v0 = *(const float4*)p;
                    v1 = *(const float4*)(p + 4);
                }
                tmp[0] = f2bf(v0.x); tmp[1] = f2bf(v0.y); tmp[2] = f2bf(v0.z); tmp[3] = f2bf(v0.w);
                tmp[4] = f2bf(v1.x); tmp[5] = f2bf(v1.y); tmp[6] = f2bf(v1.z); tmp[7] = f2bf(v1.w);
            }
            *(uint4*)&sm.s.Xs[row][kg * 8] = *(uint4*)tmp;
        }
        // stage Wt tile (128 n x 64 k): 1024 slots, 4 iters
#pragma unroll
        for (int it = 0; it < 4; it++) {
            int s5 = t + it * 256;
            int n = s5 >> 3, kg = s5 & 7;
            *(uint4*)&sm.s.Ws[n][kg * 8] = *(const uint4*)&Wt[(unsigned)(n * K + k0 + kg * 8)];
        }
        __syncthreads();
#pragma unroll
        for (int ks = 0; ks < 2; ks++) {
            int kb = ks * 32 + quad * 8;
            short8 a0 = *(const short8*)&sm.s.Xs[w * 16 + nl][kb];
#pragma unroll
            for (int ct = 0; ct < 8; ct++) {
                short8 b = *(const short8*)&sm.s.Ws[ct * 16 + nl][kb];
                acc[ct] = __builtin_amdgcn_mfma_f32_16x16x32_bf16(a0, b, acc[ct], 0, 0, 0);
            }
        }
        __syncthreads();
    }

    // acc -> Hs (bf16); wave w owns rows [w*16, w*16+16)
#pragma unroll
    for (int ct = 0; ct < 8; ct++)
#pragma unroll
        for (int r = 0; r < 4; r++)
            sm.Hs[w * 16 + quad * 4 + r][ct * 16 + nl] = f2bf(acc[ct][r]);

    float asv[8], adv[8];
    {
        const float* ap = &att_src[nl * 8];
        const float* dp = &att_dst[nl * 8];
        *(float4*)&asv[0] = *(const float4*)ap;  *(float4*)&asv[4] = *(const float4*)(ap + 4);
        *(float4*)&adv[0] = *(const float4*)dp;  *(float4*)&adv[4] = *(const float4*)(dp + 4);
    }
    int hd = nl >> 2;
#pragma unroll
    for (int it = 0; it < 4; it++) {
        int rl = w * 16 + it * 4 + quad;
        int grow = rowBase + rl;
        uint4 v = *(const uint4*)&sm.Hs[rl][nl * 8];
        float f[8];
        f[0] = __uint_as_float(v.x << 16); f[1] = __uint_as_float(v.x & 0xffff0000u);
        f[2] = __uint_as_float(v.y << 16); f[3] = __uint_as_float(v.y & 0xffff0000u);
        f[4] = __uint_as_float(v.z << 16); f[5] = __uint_as_float(v.z & 0xffff0000u);
        f[6] = __uint_as_float(v.w << 16); f[7] = __uint_as_float(v.w & 0xffff0000u);
        float ds = 0.f, dd = 0.f;
#pragma unroll
        for (int j = 0; j < 8; j++) {
            ds = fmaf(f[j], asv[j], ds);
            dd = fmaf(f[j], adv[j], dd);
        }
        ds += __shfl_xor(ds, 1); ds += __shfl_xor(ds, 2);
        dd += __shfl_xor(dd, 1); dd += __shfl_xor(dd, 2);
        if (grow < N_NODES) {
            *(uint4*)&Hout[(unsigned)(grow * HID + nl * 8)] = v;
            if ((nl & 3) == 0) { aS[grow * 4 + hd] = ds; aD[grow * 4 + hd] = dd; }
        }
    }
}

// ---------------------------------------------------------------------------
// Fused softmax + aggregate, one wave per node (head-parallel phase A,
// channel-parallel phase B with 8-deep load batching). ASTRIDE=65: phase-A
// writes land max 2-way bank-aliased (free).
// ---------------------------------------------------------------------------
#define ECAP 64
#define ASTRIDE 65

template<bool OUTBF16>
__global__ __launch_bounds__(256) void gather_kernel(const unsigned short* __restrict__ hfeat,
                                                     const float* __restrict__ a_s,
                                                     const float* __restrict__ a_d,
                                                     const int* __restrict__ starts,
                                                     const int* __restrict__ degs,
                                                     const int* __restrict__ csr,
                                                     const float* __restrict__ coefA,
                                                     const float* __restrict__ coefB,
                                                     void* __restrict__ outv) {
    __shared__ float alphaT[4][4][ASTRIDE];
    __shared__ int   offS[4][ECAP];
    int t = threadIdx.x, lane = t & 63, ws = t >> 6;
    int h = lane >> 4, l16 = lane & 15;
    int n = blockIdx.x * 4 + ws;
    int start = starts[n];
    int deg = degs[n];
    float adh = a_d[(unsigned)(n * 4 + h)];

    // ---- Phase A ----
    float e[4];
    int   sreg[4];
#pragma unroll
    for (int it = 0; it < 4; it++) {
        int j = l16 + it * 16;
        e[it] = -1e30f;
        if (j < deg) {
            int s = csr[start + j];
            sreg[it] = s;
            float as = a_s[(unsigned)(s * 4 + h)];
            float v = as + adh;
            e[it] = v > 0.f ? v : 0.2f * v;
        }
    }
    float m = fmaxf(fmaxf(e[0], e[1]), fmaxf(e[2], e[3]));
    for (int j = ECAP + l16; j < deg; j += 16) {   // rare fallback
        int s = csr[start + j];
        float as = a_s[(unsigned)(s * 4 + h)];
        float v = as + adh; v = v > 0.f ? v : 0.2f * v;
        m = fmaxf(m, v);
    }
#pragma unroll
    for (int off = 1; off < 16; off <<= 1) m = fmaxf(m, __shfl_xor(m, off));

    float x[4];
    float d = 0.f;
#pragma unroll
    for (int it = 0; it < 4; it++) { x[it] = __expf(e[it] - m); d += x[it]; }
    for (int j = ECAP + l16; j < deg; j += 16) {   // rare fallback
        int s = csr[start + j];
        float as = a_s[(unsigned)(s * 4 + h)];
        float v = as + adh; v = v > 0.f ? v : 0.2f * v;
        d += __expf(v - m);
    }
#pragma unroll
    for (int off = 1; off < 16; off <<= 1) d += __shfl_xor(d, off);
    float rd = 1.0f / (d + 1e-16f);

#pragma unroll
    for (int it = 0; it < 4; it++) {
        int j = l16 + it * 16;
        if (j < deg) {
            alphaT[ws][h][j] = x[it] * rd;
            if (h == 0) offS[ws][j] = sreg[it] << 8;
        }
    }
    __syncthreads();

    // ---- Phase B ----
    int c = lane * 2;
    int lane4 = lane * 4;
    const char* hbase = (const char*)hfeat;

    float acc0 = 0.f, acc1 = 0.f;
    int cap = deg < ECAP ? deg : ECAP;
    int j = 0;
    for (; j + 7 < cap; j += 8) {
        unsigned o[8]; float a[8]; unsigned v[8];
#pragma unroll
        for (int u = 0; u < 8; u++) o[u] = (unsigned)(offS[ws][j + u] + lane4);
#pragma unroll
        for (int u = 0; u < 8; u++) a[u] = alphaT[ws][h][j + u];
#pragma unroll
        for (int u = 0; u < 8; u++) v[u] = *(const unsigned int*)(hbase + o[u]);
#pragma unroll
        for (int u = 0; u < 8; u++) {
            acc0 = fmaf(__uint_as_float(v[u] << 16),         a[u], acc0);
            acc1 = fmaf(__uint_as_float(v[u] & 0xffff0000u), a[u], acc1);
        }
    }
    for (; j < cap; j++) {
        unsigned o = (unsigned)(offS[ws][j] + lane4);
        float al = alphaT[ws][h][j];
        unsigned int v = *(const unsigned int*)(hbase + o);
        acc0 = fmaf(__uint_as_float(v << 16),         al, acc0);
        acc1 = fmaf(__uint_as_float(v & 0xffff0000u), al, acc1);
    }
    for (; j < deg; j++) {   // rare fallback
        int s = csr[start + j];
        float as = a_s[(unsigned)(s * 4 + h)];
        float v2 = as + adh; v2 = v2 > 0.f ? v2 : 0.2f * v2;
        float al = __expf(v2 - m) * rd;
        unsigned int v = *(const unsigned int*)(hbase + (unsigned)((s << 8) + lane4));
        acc0 = fmaf(__uint_as_float(v << 16),         al, acc0);
        acc1 = fmaf(__uint_as_float(v & 0xffff0000u), al, acc1);
    }
    float2 cA = *(const float2*)&coefA[c];
    float2 cB = *(const float2*)&coefB[c];
    float o0 = fmaxf(fmaf(acc0, cA.x, cB.x), 0.f);
    float o1 = fmaxf(fmaf(acc1, cA.y, cB.y), 0.f);
    if (OUTBF16) {
        unsigned int pk = (unsigned int)f2bf(o0) | ((unsigned int)f2bf(o1) << 16);
        ((unsigned int*)outv)[(unsigned)(n * 64 + lane)] = pk;
    } else {
        ((float2*)outv)[(unsigned)(n * 64 + lane)] = make_float2(o0, o1);
    }
}

// ---------------------------------------------------------------------------
extern "C" void kernel_launch(void* const* d_in, const int* in_sizes, int n_in,
                              void* d_out, int out_size, void* d_ws, size_t ws_size,
                              hipStream_t stream) {
    const float* x    = (const float*)d_in[0];
    const int*   ei   = (const int*)d_in[1];
    const float* W1   = (const float*)d_in[2];
    const float* as1  = (const float*)d_in[3];
    const float* ad1  = (const float*)d_in[4];
    const float* b1   = (const float*)d_in[5];
    const float* g1   = (const float*)d_in[6];
    const float* be1  = (const float*)d_in[7];
    const float* mn1  = (const float*)d_in[8];
    const float* vr1  = (const float*)d_in[9];
    const float* W2   = (const float*)d_in[10];
    const float* as2  = (const float*)d_in[11];
    const float* ad2  = (const float*)d_in[12];
    const float* b2   = (const float*)d_in[13];
    const float* g2   = (const float*)d_in[14];
    const float* be2  = (const float*)d_in[15];
    const float* mn2  = (const float*)d_in[16];
    const float* vr2  = (const float*)d_in[17];
    float* out = (float*)d_out;

    unsigned short* hb  = (unsigned short*)d_ws;                  // N*128 bf16
    unsigned short* x2b = hb + (size_t)N_NODES * HID;             // N*128 bf16
    unsigned short* Wt1 = x2b + (size_t)N_NODES * HID;            // 128*256
    unsigned short* Wt2 = Wt1 + 128 * 256;                        // 128*128
    float* aS    = (float*)(Wt2 + 128 * 128);                     // N*4
    float* aD    = aS + N_NODES * NH;                             // N*4
    float* coef  = aD + N_NODES * NH;                             // 512
    int* cursor  = (int*)(coef + 512);                            // NB
    int* starts  = cursor + NB;                                   // N
    int* degs    = starts + N_NODES;                              // N
    int* binned  = degs + N_NODES;                                // NB*BCAP
    int* csr     = binned + NB * BCAP;                            // NB*BCAP

    init_cursor_kernel<<<2, 256, 0, stream>>>(cursor);
    bin_scatter_kernel<<<BIN_BLOCKS, 256, 0, stream>>>(ei, cursor, binned);
    bin_finalize_kernel<<<NB, 256, 0, stream>>>(binned, cursor, starts, degs, csr);
    wtrans_coef_kernel<<<128, 256, 0, stream>>>(W1, W2, Wt1, Wt2,
                                                b1, g1, be1, mn1, vr1,
                                                b2, g2, be2, mn2, vr2, coef);

    int gemmGrid = (N_NODES + GR - 1) / GR;   // 782
    int nodeGrid = N_NODES / 4;               // 12500

    // Layer 1
    gemm_att_kernel<false><<<gemmGrid, 256, 0, stream>>>(x, Wt1, as1, ad1, hb, aS, aD, 256);
    gather_kernel<true><<<nodeGrid, 256, 0, stream>>>(hb, aS, aD, starts, degs, csr,
                                                      coef, coef + 128, (void*)x2b);
    // Layer 2
    gemm_att_kernel<true><<<gemmGrid, 256, 0, stream>>>(x2b, Wt2, as2, ad2, hb, aS, aD, 128);
    gather_kernel<false><<<nodeGrid, 256, 0, stream>>>(hb, aS, aD, starts, degs, csr,
                                                       coef + 256, coef + 384, (void*)out);
}